// Round 3
// baseline (305.140 us; speedup 1.0000x reference)
//
#include <hip/hip_runtime.h>

#define NDET 5000
#define NCLS 80
#define DSTR 84      // 4 box coords + 80 class scores
#define TOPK 1000
#define CROP 14
#define NPIX (CROP * CROP)   // 196
#define C    256

#define JCHUNK 250           // 5000 / 20 j-chunks
#define ICHUNK 256

typedef float v4f __attribute__((ext_vector_type(4)));

// ---------------- Phase 1a: scores + zero the rank array --------------------
__global__ void scores_kernel(const float* __restrict__ det, float* __restrict__ scores,
                              int* __restrict__ rank) {
    int i = blockIdx.x * blockDim.x + threadIdx.x;
    if (i >= NDET) return;
    const float* row = det + i * DSTR + 4;
    float m = row[0];
    #pragma unroll
    for (int c = 1; c < NCLS; ++c) m = fmaxf(m, row[c]);
    scores[i] = m;
    rank[i] = 0;
}

// ---------------- Phase 1b: distributed rank counting -----------------------
// rank(i) = #{j : s_j > s_i} + #{j < i : s_j == s_i}   (jax.lax.top_k order)
__global__ __launch_bounds__(ICHUNK) void rank_kernel(const float* __restrict__ scores,
                                                      int* __restrict__ rank) {
    __shared__ float s[JCHUNK];
    int jbase = blockIdx.y * JCHUNK;
    for (int t = threadIdx.x; t < JCHUNK; t += blockDim.x) s[t] = scores[jbase + t];
    __syncthreads();
    int i = blockIdx.x * ICHUNK + threadIdx.x;
    if (i >= NDET) return;
    float my = scores[i];
    int r = 0;
    #pragma unroll 5
    for (int t = 0; t < JCHUNK; ++t) {
        float v = s[t];
        int j = jbase + t;
        r += (v > my) | ((v == my) & (j < i));
    }
    atomicAdd(&rank[i], r);
}

__global__ void scatter_kernel(const int* __restrict__ rank, int* __restrict__ topk_idx) {
    int i = blockIdx.x * blockDim.x + threadIdx.x;
    if (i >= NDET) return;
    int r = rank[i];
    if (r < TOPK) topk_idx[r] = i;
}

// ---------------- Phase 1c: levels + stable counting-sort via packed scan ---
__global__ __launch_bounds__(1024) void order_kernel(const float* __restrict__ det,
                                                     const int* __restrict__ topk_idx,
                                                     int* __restrict__ slot_det,
                                                     int* __restrict__ slot_level) {
    __shared__ unsigned long long wave_tot[16];
    int r = threadIdx.x;
    int di = 0, L = 0;
    unsigned long long key = 0;
    if (r < TOPK) {
        di = topk_idx[r];
        const float* b = det + di * DSTR;
        float w = b[2] - b[0];
        float h = b[3] - b[1];
        float sz = sqrtf(w * h);
        float lf = floorf(1.0f + log2f(sz / 224.0f + 1e-7f));
        lf = fminf(fmaxf(lf, 0.0f), 4.0f);
        L = (int)lf;
        key = 1ULL << (12 * L);
    }
    unsigned long long incl = key;
    #pragma unroll
    for (int d = 1; d < 64; d <<= 1) {
        unsigned long long up = __shfl_up(incl, d, 64);
        if ((r & 63) >= d) incl += up;
    }
    int wave = r >> 6;
    if ((r & 63) == 63) wave_tot[wave] = incl;
    __syncthreads();
    unsigned long long waveoff = 0, total = 0;
    for (int w = 0; w < 16; ++w) {
        unsigned long long t = wave_tot[w];
        if (w < wave) waveoff += t;
        total += t;
    }
    if (r < TOPK) {
        unsigned long long excl = waveoff + incl - key;
        int base = 0;
        for (int l = 0; l < L; ++l) base += (int)((total >> (12 * l)) & 0xFFF);
        int within = (int)((excl >> (12 * L)) & 0xFFF);
        int pos = base + within;
        slot_det[pos] = di;
        slot_level[pos] = L;
    }
}

// ---------------- Phase 2: crop_and_resize main kernel ----------------------
// 2 blocks per box; each wave loops over pixels p = wp + 8*j (wp in 0..7).
// Lane handles 4 contiguous channels (v4f). Nontemporal stores: output is
// write-once, keep L2 for feature gathers.
__global__ __launch_bounds__(256) void crop_kernel(
    const float* __restrict__ det,
    const float* __restrict__ p0, const float* __restrict__ p1,
    const float* __restrict__ p2, const float* __restrict__ p3,
    const float* __restrict__ p4,
    const int* __restrict__ slot_det, const int* __restrict__ slot_level,
    float* __restrict__ out)
{
    int wave = threadIdx.x >> 6;
    int lane = threadIdx.x & 63;
    int slot = blockIdx.x >> 1;
    int sub  = blockIdx.x & 1;
    int wp   = sub * 4 + wave;            // 0..7

    int di = slot_det[slot];
    int L  = slot_level[slot];

    const float* feat; int H;
    switch (L) {
        case 0:  feat = p0; H = 256; break;
        case 1:  feat = p1; H = 128; break;
        case 2:  feat = p2; H = 64;  break;
        case 3:  feat = p3; H = 32;  break;
        default: feat = p4; H = 16;  break;
    }
    float hf = (float)(H - 1);

    const float* b = det + di * DSTR;
    float x1n = b[0] / hf, y1n = b[1] / hf;
    float x2n = b[2] / hf, y2n = b[3] / hf;   // W == H per level
    float* outbase = out + (size_t)slot * NPIX * C;

    for (int p = wp; p < NPIX; p += 8) {
        int py = p / CROP;
        int px = p - py * CROP;
        float ty = (float)py / 13.0f;
        float tx = (float)px / 13.0f;
        float ys = (y1n + (y2n - y1n) * ty) * hf;
        float xs = (x1n + (x2n - x1n) * tx) * hf;

        v4f* outp = (v4f*)(outbase + (size_t)p * C) + lane;

        bool valid = (ys >= 0.0f) & (ys <= hf) & (xs >= 0.0f) & (xs <= hf);
        if (!valid) {
            v4f z = {0.0f, 0.0f, 0.0f, 0.0f};
            __builtin_nontemporal_store(z, outp);
            continue;
        }

        float y0f = floorf(ys), x0f = floorf(xs);
        float ly = ys - y0f,    lx = xs - x0f;
        int y0i = (int)fminf(fmaxf(y0f,        0.0f), hf);
        int y1i = (int)fminf(fmaxf(y0f + 1.0f, 0.0f), hf);
        int x0i = (int)fminf(fmaxf(x0f,        0.0f), hf);
        int x1i = (int)fminf(fmaxf(x0f + 1.0f, 0.0f), hf);

        v4f f00 = ((const v4f*)(feat + (size_t)(y0i * H + x0i) * C))[lane];
        v4f f01 = ((const v4f*)(feat + (size_t)(y0i * H + x1i) * C))[lane];
        v4f f10 = ((const v4f*)(feat + (size_t)(y1i * H + x0i) * C))[lane];
        v4f f11 = ((const v4f*)(feat + (size_t)(y1i * H + x1i) * C))[lane];

        v4f top = f00 + (f01 - f00) * lx;
        v4f bot = f10 + (f11 - f10) * lx;
        v4f o   = top + (bot - top) * ly;
        __builtin_nontemporal_store(o, outp);
    }
}

extern "C" void kernel_launch(void* const* d_in, const int* in_sizes, int n_in,
                              void* d_out, int out_size, void* d_ws, size_t ws_size,
                              hipStream_t stream) {
    const float* det = (const float*)d_in[0];
    const float* p0  = (const float*)d_in[1];
    const float* p1  = (const float*)d_in[2];
    const float* p2  = (const float*)d_in[3];
    const float* p3  = (const float*)d_in[4];
    const float* p4  = (const float*)d_in[5];
    float* out = (float*)d_out;

    char* ws = (char*)d_ws;
    float* scores    = (float*)(ws + 0);          // 5000 floats
    int*   rank      = (int*)(ws + 20000);        // 5000 ints
    int*   topk_idx  = (int*)(ws + 40000);        // 1000 ints
    int*   slot_det  = (int*)(ws + 44000);        // 1000 ints
    int*   slot_lvl  = (int*)(ws + 48000);        // 1000 ints

    scores_kernel<<<(NDET + 255) / 256, 256, 0, stream>>>(det, scores, rank);
    dim3 rg((NDET + ICHUNK - 1) / ICHUNK, NDET / JCHUNK);
    rank_kernel<<<rg, ICHUNK, 0, stream>>>(scores, rank);
    scatter_kernel<<<(NDET + 255) / 256, 256, 0, stream>>>(rank, topk_idx);
    order_kernel<<<1, 1024, 0, stream>>>(det, topk_idx, slot_det, slot_lvl);
    crop_kernel<<<TOPK * 2, 256, 0, stream>>>(det, p0, p1, p2, p3, p4,
                                              slot_det, slot_lvl, out);
}